// Round 5
// baseline (150.026 us; speedup 1.0000x reference)
//
#include <hip/hip_runtime.h>

#define BB 32
#define NN 512
#define PP 128
#define MM (BB * NN)  // 16384 rows

typedef unsigned long long ull;

// ws layout (float offsets) — VERBATIM from round-2 (proven in-bounds, 2.1 MB)
#define POSP_OFF 0            // [8][MM] f32
#define NEGP_OFF (8 * MM)     // [8][MM] f32
#define UVB_OFF (16 * MM)     // u[128], v[128], bias[128]
#define MASK_OFF_BYTES ((size_t)(16 * MM + 512) * 4)  // [8][MM] u64, 8B-aligned

// u[p] = sum_q relu(t[q])*W3[q][p]; v likewise with -t; bias = b1+b2+b3
__global__ void k_uv(const float* __restrict__ t4, const float* __restrict__ W3,
                     const float* __restrict__ b1, const float* __restrict__ b2,
                     const float* __restrict__ b3, float* __restrict__ uvb) {
    int p = threadIdx.x;
    float u = 0.f, v = 0.f;
    for (int q = 0; q < PP; ++q) {
        float t = t4[q];
        float w = W3[q * PP + p];
        u += fmaxf(t, 0.f) * w;
        v += fmaxf(-t, 0.f) * w;
    }
    uvb[p] = u;
    uvb[PP + p] = v;
    uvb[2 * PP + p] = b1[p] + b2[p] + b3[p];
}

// Per (b, i-segment, j): partial pos/neg + 64-bit neighbor mask word.
// Mask bit k of word seg = adj[b, seg*64+k, j] != 0  (exactly the axis-1 mask).
__global__ __launch_bounds__(256) void k_prep(const float* __restrict__ weight,
                                              const float* __restrict__ adj,
                                              float* __restrict__ posP,
                                              float* __restrict__ negP,
                                              ull* __restrict__ maskb) {
    int b = blockIdx.z, seg = blockIdx.y;
    int j = blockIdx.x * 256 + threadIdx.x;
    size_t base = (size_t)b * NN * NN + (size_t)seg * 64 * NN + j;
    const float* wp = weight + base;
    const float* ap = adj + base;
    float ps = 0.f, ng = 0.f;
    ull m = 0;
#pragma unroll 8
    for (int k = 0; k < 64; ++k) {
        float a = ap[(size_t)k * NN];
        float w = wp[(size_t)k * NN];
        if (a != 0.f) {
            m |= (1ull << k);
            ps += fmaxf(w, 0.f);
            ng += fmaxf(-w, 0.f);
        }
    }
    int row = b * NN + j;
    posP[seg * MM + row] = ps;
    negP[seg * MM + row] = ng;
    maskb[(size_t)seg * MM + row] = m;
}

// Fused: per-wave sparse gather of mu rows -> LDS -> @W2 -> epilogue.
// 512 threads = 8 waves; 8 rows/block (1 row per wave); 2048 blocks.
// Phase 2: wave w stays on its own row w; lane owns p = 2*lane + {0,1}.
__global__ __launch_bounds__(512) void k_main(
    const float* __restrict__ x, const float* __restrict__ mu,
    const float* __restrict__ W1, const float* __restrict__ W2,
    const float* __restrict__ posP, const float* __restrict__ negP,
    const float* __restrict__ uvb, const ull* __restrict__ maskb,
    float* __restrict__ out) {
    __shared__ float aggL[8 * 130];

    int bid = blockIdx.x;
    int vbid = ((bid & 7) << 8) | (bid >> 3);  // bijective 8x256 transpose (XCD chunking)
    int row0 = vbid * 8;
    int b = row0 >> 9;
    int tx = threadIdx.x;
    int lane = tx & 63, w = tx >> 6;

    const float2* mub2 = (const float2*)(mu + (size_t)b * NN * PP);

    // ---- phase 1 (round-2 body, rloc = w): agg[row][p] = sum_{i in mask} mu[b,i,p] ----
    {
        int rloc = w;
        int row = row0 + rloc;
        float ax = 0.f, ay = 0.f;
#pragma unroll
        for (int r = 0; r < 8; ++r) {
            uint2 mw = ((const uint2*)maskb)[(size_t)r * MM + row];
            unsigned lo = __builtin_amdgcn_readfirstlane(mw.x);
            unsigned hi = __builtin_amdgcn_readfirstlane(mw.y);
            ull mask = ((ull)hi << 32) | lo;
            int ib = r * 64;
            while (mask) {
                int i0 = __builtin_ctzll(mask);
                mask &= mask - 1;
                float2 v0 = mub2[(size_t)((ib + i0) << 6) | lane];
                if (mask) {
                    int i1 = __builtin_ctzll(mask);
                    mask &= mask - 1;
                    float2 v1 = mub2[(size_t)((ib + i1) << 6) | lane];
                    ax += v0.x; ay += v0.y;
                    ax += v1.x; ay += v1.y;
                } else {
                    ax += v0.x; ay += v0.y;
                }
            }
        }
        *(float2*)&aggL[rloc * 130 + 2 * lane] = make_float2(ax, ay);
    }
    __syncthreads();

    // ---- phase 2: out = relu(agg@W2 + x*W1 + pos*u + neg*v + bias) ----
    // wave w -> row w; lane -> columns p0, p0+1. Per-wave W2 reads are 512B coalesced.
    int rowg = w;
    int p0 = lane * 2;
    float c0 = 0.f, c1 = 0.f;
    const float* agr = &aggL[rowg * 130];
#pragma unroll 4
    for (int q = 0; q < PP; ++q) {
        float a = agr[q];
        const float2 w2 = *(const float2*)&W2[q * PP + p0];
        c0 += a * w2.x;
        c1 += a * w2.y;
    }

    int row = row0 + rowg;
    float xs = x[row];
    float ps = 0.f, ng = 0.f;
#pragma unroll
    for (int s = 0; s < 8; ++s) {
        ps += posP[s * MM + row];
        ng += negP[s * MM + row];
    }
    {
        int p = p0;
        float o = c0 + xs * W1[p] + ps * uvb[p] + ng * uvb[PP + p] + uvb[2 * PP + p];
        out[(size_t)row * PP + p] = fmaxf(o, 0.f);
        p = p0 + 1;
        o = c1 + xs * W1[p] + ps * uvb[p] + ng * uvb[PP + p] + uvb[2 * PP + p];
        out[(size_t)row * PP + p] = fmaxf(o, 0.f);
    }
}

extern "C" void kernel_launch(void* const* d_in, const int* in_sizes, int n_in,
                              void* d_out, int out_size, void* d_ws, size_t ws_size,
                              hipStream_t stream) {
    const float* x      = (const float*)d_in[0];
    const float* mu     = (const float*)d_in[1];
    const float* weight = (const float*)d_in[2];
    const float* adj    = (const float*)d_in[3];
    const float* W1     = (const float*)d_in[4];
    const float* b1     = (const float*)d_in[5];
    const float* W2     = (const float*)d_in[6];
    const float* b2     = (const float*)d_in[7];
    const float* W3     = (const float*)d_in[8];
    const float* b3     = (const float*)d_in[9];
    const float* theta4 = (const float*)d_in[10];
    float* out = (float*)d_out;

    float* ws   = (float*)d_ws;
    float* posP = ws + POSP_OFF;
    float* negP = ws + NEGP_OFF;
    float* uvb  = ws + UVB_OFF;
    ull* maskb  = (ull*)((char*)d_ws + MASK_OFF_BYTES);

    k_uv<<<1, PP, 0, stream>>>(theta4, W3, b1, b2, b3, uvb);

    dim3 gp(NN / 256, 8, BB);
    k_prep<<<gp, 256, 0, stream>>>(weight, adj, posP, negP, maskb);

    k_main<<<MM / 8, 512, 0, stream>>>(x, mu, W1, W2, posP, negP, uvb, maskb, out);
}

// Round 6
// 107.243 us; speedup vs baseline: 1.3989x; 1.3989x over previous
//
#include <hip/hip_runtime.h>

#define BB 32
#define NN 512
#define PP 128
#define MM (BB * NN)  // 16384 rows

typedef unsigned int u32;
typedef unsigned long long ull;

// ws layout (float offsets) — VERBATIM from round-2/5 (proven in-bounds, 2.1 MB)
#define POSP_OFF 0            // [8][MM] f32
#define NEGP_OFF (8 * MM)     // [8][MM] f32
#define UVB_OFF (16 * MM)     // u[128], v[128], bias[128]
#define MASK_OFF_BYTES ((size_t)(16 * MM + 512) * 4)  // [8][MM] u64, 8B-aligned

__device__ inline u32 bf16rne(float f) {
    u32 u = __float_as_uint(f);
    return (u + 0x7FFFu + ((u >> 16) & 1u)) >> 16;
}

// u[p] = sum_q relu(t[q])*W3[q][p]; v likewise with -t; bias = b1+b2+b3
__global__ void k_uv(const float* __restrict__ t4, const float* __restrict__ W3,
                     const float* __restrict__ b1, const float* __restrict__ b2,
                     const float* __restrict__ b3, float* __restrict__ uvb) {
    int p = threadIdx.x;
    float u = 0.f, v = 0.f;
    for (int q = 0; q < PP; ++q) {
        float t = t4[q];
        float w = W3[q * PP + p];
        u += fmaxf(t, 0.f) * w;
        v += fmaxf(-t, 0.f) * w;
    }
    uvb[p] = u;
    uvb[PP + p] = v;
    uvb[2 * PP + p] = b1[p] + b2[p] + b3[p];
}

// Per (b, i-segment, j): partial pos/neg + 64-bit neighbor mask word. (r5 verbatim)
__global__ __launch_bounds__(256) void k_prep(const float* __restrict__ weight,
                                              const float* __restrict__ adj,
                                              float* __restrict__ posP,
                                              float* __restrict__ negP,
                                              ull* __restrict__ maskb) {
    int b = blockIdx.z, seg = blockIdx.y;
    int j = blockIdx.x * 256 + threadIdx.x;
    size_t base = (size_t)b * NN * NN + (size_t)seg * 64 * NN + j;
    const float* wp = weight + base;
    const float* ap = adj + base;
    float ps = 0.f, ng = 0.f;
    ull m = 0;
#pragma unroll 8
    for (int k = 0; k < 64; ++k) {
        float a = ap[(size_t)k * NN];
        float w = wp[(size_t)k * NN];
        if (a != 0.f) {
            m |= (1ull << k);
            ps += fmaxf(w, 0.f);
            ng += fmaxf(-w, 0.f);
        }
    }
    int row = b * NN + j;
    posP[seg * MM + row] = ps;
    negP[seg * MM + row] = ng;
    maskb[(size_t)seg * MM + row] = m;
}

// Fused: per-wave sparse gather of mu rows -> LDS -> @W2(bf16 in LDS) -> epilogue.
// 512 threads = 8 waves; 8 rows/block (1 row per wave); 2048 blocks.
__global__ __launch_bounds__(512) void k_main(
    const float* __restrict__ x, const float* __restrict__ mu,
    const float* __restrict__ W1, const float* __restrict__ W2,
    const float* __restrict__ posP, const float* __restrict__ negP,
    const float* __restrict__ uvb, const ull* __restrict__ maskb,
    float* __restrict__ out) {
    __shared__ float aggL[8 * 130];
    __shared__ u32 w2L[PP * PP / 2];  // 32 KB: row q, packed col-pairs: w2L[q*64+c] = bf16(W2[q][2c+1])<<16 | bf16(W2[q][2c])

    int bid = blockIdx.x;
    int vbid = ((bid & 7) << 8) | (bid >> 3);  // bijective 8x256 transpose (XCD chunking)
    int row0 = vbid * 8;
    int b = row0 >> 9;
    int tx = threadIdx.x;
    int lane = tx & 63, w = tx >> 6;

    // ---- issue W2 prefetch into registers (16 float2 per thread, 8192 pairs total).
    // Loads stay in flight during the gather; LDS write + convert happens after.
    float2 w2r[16];
    const float2* W2v = (const float2*)W2;
#pragma unroll
    for (int s = 0; s < 16; ++s) w2r[s] = W2v[s * 512 + tx];

    const float2* mub2 = (const float2*)(mu + (size_t)b * NN * PP);

    // ---- phase 1 (r5 verbatim): agg[row][p] = sum_{i in mask} mu[b,i,p] ----
    {
        int rloc = w;
        int row = row0 + rloc;
        float ax = 0.f, ay = 0.f;
#pragma unroll
        for (int r = 0; r < 8; ++r) {
            uint2 mw = ((const uint2*)maskb)[(size_t)r * MM + row];
            unsigned lo = __builtin_amdgcn_readfirstlane(mw.x);
            unsigned hi = __builtin_amdgcn_readfirstlane(mw.y);
            ull mask = ((ull)hi << 32) | lo;
            int ib = r * 64;
            while (mask) {
                int i0 = __builtin_ctzll(mask);
                mask &= mask - 1;
                float2 v0 = mub2[(size_t)((ib + i0) << 6) | lane];
                if (mask) {
                    int i1 = __builtin_ctzll(mask);
                    mask &= mask - 1;
                    float2 v1 = mub2[(size_t)((ib + i1) << 6) | lane];
                    ax += v0.x; ay += v0.y;
                    ax += v1.x; ay += v1.y;
                } else {
                    ax += v0.x; ay += v0.y;
                }
            }
        }
        *(float2*)&aggL[rloc * 130 + 2 * lane] = make_float2(ax, ay);
    }

    // ---- convert prefetched W2 to packed bf16 in LDS ----
#pragma unroll
    for (int s = 0; s < 16; ++s)
        w2L[s * 512 + tx] = (bf16rne(w2r[s].y) << 16) | bf16rne(w2r[s].x);

    __syncthreads();

    // ---- phase 2: out = relu(agg@W2 + x*W1 + pos*u + neg*v + bias) ----
    // wave w -> row w; lane -> columns p0, p0+1. W2 from LDS (2-way aliasing = free).
    int rowg = w;
    int p0 = lane * 2;
    float c0 = 0.f, c1 = 0.f;
    const float* agr = &aggL[rowg * 130];
#pragma unroll 4
    for (int q = 0; q < PP; ++q) {
        float a = agr[q];          // same addr across wave: LDS broadcast
        u32 wp = w2L[q * 64 + lane];
        float w0 = __uint_as_float(wp << 16);
        float w1 = __uint_as_float(wp & 0xFFFF0000u);
        c0 += a * w0;
        c1 += a * w1;
    }

    int row = row0 + rowg;
    float xs = x[row];
    float ps = 0.f, ng = 0.f;
#pragma unroll
    for (int s = 0; s < 8; ++s) {
        ps += posP[s * MM + row];
        ng += negP[s * MM + row];
    }
    {
        int p = p0;
        float o = c0 + xs * W1[p] + ps * uvb[p] + ng * uvb[PP + p] + uvb[2 * PP + p];
        out[(size_t)row * PP + p] = fmaxf(o, 0.f);
        p = p0 + 1;
        o = c1 + xs * W1[p] + ps * uvb[p] + ng * uvb[PP + p] + uvb[2 * PP + p];
        out[(size_t)row * PP + p] = fmaxf(o, 0.f);
    }
}

extern "C" void kernel_launch(void* const* d_in, const int* in_sizes, int n_in,
                              void* d_out, int out_size, void* d_ws, size_t ws_size,
                              hipStream_t stream) {
    const float* x      = (const float*)d_in[0];
    const float* mu     = (const float*)d_in[1];
    const float* weight = (const float*)d_in[2];
    const float* adj    = (const float*)d_in[3];
    const float* W1     = (const float*)d_in[4];
    const float* b1     = (const float*)d_in[5];
    const float* W2     = (const float*)d_in[6];
    const float* b2     = (const float*)d_in[7];
    const float* W3     = (const float*)d_in[8];
    const float* b3     = (const float*)d_in[9];
    const float* theta4 = (const float*)d_in[10];
    float* out = (float*)d_out;

    float* ws   = (float*)d_ws;
    float* posP = ws + POSP_OFF;
    float* negP = ws + NEGP_OFF;
    float* uvb  = ws + UVB_OFF;
    ull* maskb  = (ull*)((char*)d_ws + MASK_OFF_BYTES);

    k_uv<<<1, PP, 0, stream>>>(theta4, W3, b1, b2, b3, uvb);

    dim3 gp(NN / 256, 8, BB);
    k_prep<<<gp, 256, 0, stream>>>(weight, adj, posP, negP, maskb);

    k_main<<<MM / 8, 512, 0, stream>>>(x, mu, W1, W2, posP, negP, uvb, maskb, out);
}

// Round 7
// 90.007 us; speedup vs baseline: 1.6668x; 1.1915x over previous
//
#include <hip/hip_runtime.h>

#define BB 32
#define NN 512
#define PP 128
#define MM (BB * NN)  // 16384 rows

typedef unsigned int u32;
typedef unsigned long long ull;

// ws layout (float offsets) — VERBATIM from round-2/5/6 (proven in-bounds, 2.1 MB)
#define POSP_OFF 0            // [8][MM] f32
#define NEGP_OFF (8 * MM)     // [8][MM] f32
#define UVB_OFF (16 * MM)     // u[128], v[128], bias[128]
#define MASK_OFF_BYTES ((size_t)(16 * MM + 512) * 4)  // [8][MM] u64, 8B-aligned

__device__ inline u32 bf16rne(float f) {
    u32 u = __float_as_uint(f);
    return (u + 0x7FFFu + ((u >> 16) & 1u)) >> 16;
}

// uv: 256 thr, two q-halves reduced in LDS. bias = b1+b2+b3.
__global__ __launch_bounds__(256) void k_uv(const float* __restrict__ t4,
                                            const float* __restrict__ W3,
                                            const float* __restrict__ b1,
                                            const float* __restrict__ b2,
                                            const float* __restrict__ b3,
                                            float* __restrict__ uvb) {
    __shared__ float su[2][PP], sv[2][PP];
    int p = threadIdx.x & 127, h = threadIdx.x >> 7;
    float u = 0.f, v = 0.f;
#pragma unroll 8
    for (int q = h * 64; q < h * 64 + 64; ++q) {
        float t = t4[q];
        float w = W3[q * PP + p];
        u += fmaxf(t, 0.f) * w;
        v += fmaxf(-t, 0.f) * w;
    }
    su[h][p] = u;
    sv[h][p] = v;
    __syncthreads();
    if (threadIdx.x < PP) {
        uvb[p] = su[0][p] + su[1][p];
        uvb[PP + p] = sv[0][p] + sv[1][p];
        uvb[2 * PP + p] = b1[p] + b2[p] + b3[p];
    }
}

// prep: 1024 blocks (4 j-tiles x 8 segs x 32 b), 256 thr = 128 j x 2 i-halves.
// Bit semantics unchanged: maskb[seg][row] bit k = adj[b, seg*64+k, j] != 0.
__global__ __launch_bounds__(256) void k_prep(const float* __restrict__ weight,
                                              const float* __restrict__ adj,
                                              float* __restrict__ posP,
                                              float* __restrict__ negP,
                                              ull* __restrict__ maskb) {
    __shared__ float sps[2][128], sng[2][128];
    __shared__ u32 sm[2][128];

    int b = blockIdx.z, seg = blockIdx.y;
    int tx = threadIdx.x;
    int jl = tx & 127, half = tx >> 7;
    int j = blockIdx.x * 128 + jl;

    size_t base = (size_t)b * NN * NN + ((size_t)seg * 64 + half * 32) * NN + j;
    const float* wp = weight + base;
    const float* ap = adj + base;
    float ps = 0.f, ng = 0.f;
    u32 m = 0;
#pragma unroll 8
    for (int k = 0; k < 32; ++k) {
        float a = ap[(size_t)k * NN];
        float w = wp[(size_t)k * NN];
        if (a != 0.f) {
            m |= (1u << k);
            ps += fmaxf(w, 0.f);
            ng += fmaxf(-w, 0.f);
        }
    }
    sps[half][jl] = ps;
    sng[half][jl] = ng;
    sm[half][jl] = m;
    __syncthreads();
    if (tx < 128) {
        int row = b * NN + blockIdx.x * 128 + tx;
        posP[seg * MM + row] = sps[0][tx] + sps[1][tx];
        negP[seg * MM + row] = sng[0][tx] + sng[1][tx];
        maskb[(size_t)seg * MM + row] = (ull)sm[0][tx] | ((ull)sm[1][tx] << 32);
    }
}

// Fused: 2048 blocks x 1024 thr (16 waves). 8 rows/block; TWO waves per row
// (wave w<8: mask words 0..3 of row w; wave w>=8: words 4..7 of row w-8).
// LDS merge, then waves 0..7 do @W2 (bf16 q-pair packed) + epilogue.
__global__ __launch_bounds__(1024) void k_main(
    const float* __restrict__ x, const float* __restrict__ mu,
    const float* __restrict__ W1, const float* __restrict__ W2,
    const float* __restrict__ posP, const float* __restrict__ negP,
    const float* __restrict__ uvb, const ull* __restrict__ maskb,
    float* __restrict__ out) {
    __shared__ float aggL[2][8 * 130];
    __shared__ u32 w2q[64 * PP];  // 32 KB: w2q[qq*128+p] = bf16(W2[2qq][p]) | bf16(W2[2qq+1][p])<<16

    int bid = blockIdx.x;
    int vbid = ((bid & 7) << 8) | (bid >> 3);  // bijective 8x256 transpose (XCD chunking)
    int row0 = vbid * 8;
    int b = row0 >> 9;
    int tx = threadIdx.x;
    int lane = tx & 63, w = tx >> 6;
    int rloc = w & 7, part = w >> 3;

    // ---- issue W2 prefetch (16 dword loads/thread); convert after gather ----
    float w2a[8], w2b[8];
#pragma unroll
    for (int s = 0; s < 8; ++s) {
        int n = s * 1024 + tx;
        int qq = n >> 7, p = n & 127;
        w2a[s] = W2[(2 * qq) * PP + p];
        w2b[s] = W2[(2 * qq) * PP + PP + p];
    }

    const float2* mub2 = (const float2*)(mu + (size_t)b * NN * PP);

    // ---- phase 1 (r5-verbatim gather body; this wave's 4 mask words) ----
    {
        int row = row0 + rloc;
        float ax = 0.f, ay = 0.f;
#pragma unroll
        for (int rr = 0; rr < 4; ++rr) {
            int r = part * 4 + rr;
            uint2 mw = ((const uint2*)maskb)[(size_t)r * MM + row];
            unsigned lo = __builtin_amdgcn_readfirstlane(mw.x);
            unsigned hi = __builtin_amdgcn_readfirstlane(mw.y);
            ull mask = ((ull)hi << 32) | lo;
            int ib = r * 64;
            while (mask) {
                int i0 = __builtin_ctzll(mask);
                mask &= mask - 1;
                float2 v0 = mub2[(size_t)((ib + i0) << 6) | lane];
                if (mask) {
                    int i1 = __builtin_ctzll(mask);
                    mask &= mask - 1;
                    float2 v1 = mub2[(size_t)((ib + i1) << 6) | lane];
                    ax += v0.x; ay += v0.y;
                    ax += v1.x; ay += v1.y;
                } else {
                    ax += v0.x; ay += v0.y;
                }
            }
        }
        *(float2*)&aggL[part][rloc * 130 + 2 * lane] = make_float2(ax, ay);
    }

    // ---- convert prefetched W2 to q-pair-packed bf16 in LDS ----
#pragma unroll
    for (int s = 0; s < 8; ++s) {
        int n = s * 1024 + tx;
        w2q[n] = bf16rne(w2a[s]) | (bf16rne(w2b[s]) << 16);
    }

    __syncthreads();

    // ---- merge the two half-row partials ----
    {
        int r = tx >> 7, q = tx & 127;
        aggL[0][r * 130 + q] += aggL[1][r * 130 + q];
    }
    __syncthreads();

    // ---- phase 2 (waves 0..7): out = relu(agg@W2 + x*W1 + pos*u + neg*v + bias) ----
    if (w < 8) {
        int rowg = w;
        int p0 = lane * 2;
        float c0 = 0.f, c1 = 0.f;
        const float* agr = &aggL[0][rowg * 130];
#pragma unroll 4
        for (int qq = 0; qq < 64; ++qq) {
            float2 a2 = *(const float2*)&agr[2 * qq];      // broadcast b64
            uint2 wp = *(const uint2*)&w2q[qq * PP + p0];  // 2 cols' packed q-pair
            float w00 = __uint_as_float(wp.x << 16);
            float w01 = __uint_as_float(wp.x & 0xFFFF0000u);
            float w10 = __uint_as_float(wp.y << 16);
            float w11 = __uint_as_float(wp.y & 0xFFFF0000u);
            c0 += a2.x * w00 + a2.y * w01;
            c1 += a2.x * w10 + a2.y * w11;
        }

        int row = row0 + rowg;
        float xs = x[row];
        float ps = 0.f, ng = 0.f;
#pragma unroll
        for (int s = 0; s < 8; ++s) {
            ps += posP[s * MM + row];
            ng += negP[s * MM + row];
        }
        int p = p0;
        float o = c0 + xs * W1[p] + ps * uvb[p] + ng * uvb[PP + p] + uvb[2 * PP + p];
        out[(size_t)row * PP + p] = fmaxf(o, 0.f);
        p = p0 + 1;
        o = c1 + xs * W1[p] + ps * uvb[p] + ng * uvb[PP + p] + uvb[2 * PP + p];
        out[(size_t)row * PP + p] = fmaxf(o, 0.f);
    }
}

extern "C" void kernel_launch(void* const* d_in, const int* in_sizes, int n_in,
                              void* d_out, int out_size, void* d_ws, size_t ws_size,
                              hipStream_t stream) {
    const float* x      = (const float*)d_in[0];
    const float* mu     = (const float*)d_in[1];
    const float* weight = (const float*)d_in[2];
    const float* adj    = (const float*)d_in[3];
    const float* W1     = (const float*)d_in[4];
    const float* b1     = (const float*)d_in[5];
    const float* W2     = (const float*)d_in[6];
    const float* b2     = (const float*)d_in[7];
    const float* W3     = (const float*)d_in[8];
    const float* b3     = (const float*)d_in[9];
    const float* theta4 = (const float*)d_in[10];
    float* out = (float*)d_out;

    float* ws   = (float*)d_ws;
    float* posP = ws + POSP_OFF;
    float* negP = ws + NEGP_OFF;
    float* uvb  = ws + UVB_OFF;
    ull* maskb  = (ull*)((char*)d_ws + MASK_OFF_BYTES);

    k_uv<<<1, 256, 0, stream>>>(theta4, W3, b1, b2, b3, uvb);

    dim3 gp(NN / 128, 8, BB);
    k_prep<<<gp, 256, 0, stream>>>(weight, adj, posP, negP, maskb);

    k_main<<<MM / 8, 1024, 0, stream>>>(x, mu, W1, W2, posP, negP, uvb, maskb, out);
}

// Round 8
// 83.764 us; speedup vs baseline: 1.7911x; 1.0745x over previous
//
#include <hip/hip_runtime.h>

#define BB 32
#define NN 512
#define PP 128
#define MM (BB * NN)  // 16384 rows

typedef unsigned int u32;
typedef unsigned long long ull;

// ws layout (float offsets) — VERBATIM from rounds 2/5/6/7 (proven in-bounds)
#define POSP_OFF 0            // [8][MM] f32
#define NEGP_OFF (8 * MM)     // [8][MM] f32
#define UVB_OFF (16 * MM)     // u[128], v[128], bias[128]
#define MASK_OFF_BYTES ((size_t)(16 * MM + 512) * 4)  // [8][MM] u64, 8B-aligned

__device__ inline u32 bf16rne(float f) {
    u32 u = __float_as_uint(f);
    return (u + 0x7FFFu + ((u >> 16) & 1u)) >> 16;
}

// uv: 256 thr, two q-halves reduced in LDS. bias = b1+b2+b3. (r7 verbatim)
__global__ __launch_bounds__(256) void k_uv(const float* __restrict__ t4,
                                            const float* __restrict__ W3,
                                            const float* __restrict__ b1,
                                            const float* __restrict__ b2,
                                            const float* __restrict__ b3,
                                            float* __restrict__ uvb) {
    __shared__ float su[2][PP], sv[2][PP];
    int p = threadIdx.x & 127, h = threadIdx.x >> 7;
    float u = 0.f, v = 0.f;
#pragma unroll 8
    for (int q = h * 64; q < h * 64 + 64; ++q) {
        float t = t4[q];
        float w = W3[q * PP + p];
        u += fmaxf(t, 0.f) * w;
        v += fmaxf(-t, 0.f) * w;
    }
    su[h][p] = u;
    sv[h][p] = v;
    __syncthreads();
    if (threadIdx.x < PP) {
        uvb[p] = su[0][p] + su[1][p];
        uvb[PP + p] = sv[0][p] + sv[1][p];
        uvb[2 * PP + p] = b1[p] + b2[p] + b3[p];
    }
}

// prep (r7 verbatim): 1024 blocks, 256 thr = 128 j x 2 i-halves.
__global__ __launch_bounds__(256) void k_prep(const float* __restrict__ weight,
                                              const float* __restrict__ adj,
                                              float* __restrict__ posP,
                                              float* __restrict__ negP,
                                              ull* __restrict__ maskb) {
    __shared__ float sps[2][128], sng[2][128];
    __shared__ u32 sm[2][128];

    int b = blockIdx.z, seg = blockIdx.y;
    int tx = threadIdx.x;
    int jl = tx & 127, half = tx >> 7;
    int j = blockIdx.x * 128 + jl;

    size_t base = (size_t)b * NN * NN + ((size_t)seg * 64 + half * 32) * NN + j;
    const float* wp = weight + base;
    const float* ap = adj + base;
    float ps = 0.f, ng = 0.f;
    u32 m = 0;
#pragma unroll 8
    for (int k = 0; k < 32; ++k) {
        float a = ap[(size_t)k * NN];
        float w = wp[(size_t)k * NN];
        if (a != 0.f) {
            m |= (1u << k);
            ps += fmaxf(w, 0.f);
            ng += fmaxf(-w, 0.f);
        }
    }
    sps[half][jl] = ps;
    sng[half][jl] = ng;
    sm[half][jl] = m;
    __syncthreads();
    if (tx < 128) {
        int row = b * NN + blockIdx.x * 128 + tx;
        posP[seg * MM + row] = sps[0][tx] + sps[1][tx];
        negP[seg * MM + row] = sng[0][tx] + sng[1][tx];
        maskb[(size_t)seg * MM + row] = (ull)sm[0][tx] | ((ull)sm[1][tx] << 32);
    }
}

// k_gather: 4096 blocks x 256 thr (4 waves). One row per wave, no barriers.
// Writes agg fp32 into d_out (staging; k_gemm overwrites after reading).
// Body = r5-proven mask walk, extended to 4 loads in flight.
__global__ __launch_bounds__(256) void k_gather(const float* __restrict__ mu,
                                                const ull* __restrict__ maskb,
                                                float* __restrict__ aggout) {
    int bid = blockIdx.x;
    int vbid = ((bid & 7) << 9) | (bid >> 3);  // bijective: XCD x owns 2048 consecutive rows (4 b's)
    int row0 = vbid * 4;
    int b = row0 >> 9;
    int tx = threadIdx.x, lane = tx & 63, w = tx >> 6;

    const float2* mub2 = (const float2*)(mu + (size_t)b * NN * PP);
    int row = row0 + w;
    float ax = 0.f, ay = 0.f;
#pragma unroll
    for (int r = 0; r < 8; ++r) {
        uint2 mw = ((const uint2*)maskb)[(size_t)r * MM + row];
        unsigned lo = __builtin_amdgcn_readfirstlane(mw.x);
        unsigned hi = __builtin_amdgcn_readfirstlane(mw.y);
        ull mask = ((ull)hi << 32) | lo;
        int ib = r * 64;
        while (mask) {
            int i0 = __builtin_ctzll(mask);
            mask &= mask - 1;
            float2 v0 = mub2[(size_t)((ib + i0) << 6) | lane];
            if (mask) {
                int i1 = __builtin_ctzll(mask);
                mask &= mask - 1;
                float2 v1 = mub2[(size_t)((ib + i1) << 6) | lane];
                if (mask) {
                    int i2 = __builtin_ctzll(mask);
                    mask &= mask - 1;
                    float2 v2 = mub2[(size_t)((ib + i2) << 6) | lane];
                    if (mask) {
                        int i3 = __builtin_ctzll(mask);
                        mask &= mask - 1;
                        float2 v3 = mub2[(size_t)((ib + i3) << 6) | lane];
                        ax += v0.x + v1.x + v2.x + v3.x;
                        ay += v0.y + v1.y + v2.y + v3.y;
                    } else {
                        ax += v0.x + v1.x + v2.x;
                        ay += v0.y + v1.y + v2.y;
                    }
                } else {
                    ax += v0.x + v1.x;
                    ay += v0.y + v1.y;
                }
            } else {
                ax += v0.x;
                ay += v0.y;
            }
        }
    }
    *(float2*)&aggout[(size_t)row * PP + 2 * lane] = make_float2(ax, ay);
}

// k_gemm: 512 blocks x 512 thr (8 waves). 32 rows/block.
// Stage agg (from d_out) + W2(bf16 q-pair) in LDS, compute, overwrite d_out.
__global__ __launch_bounds__(512) void k_gemm(
    const float* __restrict__ x, const float* __restrict__ W1,
    const float* __restrict__ W2, const float* __restrict__ posP,
    const float* __restrict__ negP, const float* __restrict__ uvb,
    float* __restrict__ out) {
    __shared__ float aggL[32][130];  // 16.6 KB
    __shared__ u32 w2q[64 * PP];     // 32 KB: w2q[qq*128+p] = bf16(W2[2qq][p]) | bf16(W2[2qq+1][p])<<16

    int bid = blockIdx.x;
    int vbid = ((bid & 7) << 6) | (bid >> 3);  // same-XCD rows as k_gather
    int row0 = vbid * 32;
    int tx = threadIdx.x, lane = tx & 63, w = tx >> 6;

    // stage W2 -> packed bf16 LDS (8192 entries, 16/thread)
#pragma unroll
    for (int s = 0; s < 16; ++s) {
        int n = s * 512 + tx;
        int qq = n >> 7, p = n & 127;
        w2q[n] = bf16rne(W2[(2 * qq) * PP + p]) | (bf16rne(W2[(2 * qq) * PP + PP + p]) << 16);
    }
    // stage agg rows (2048 float2, 4/thread), coalesced
#pragma unroll
    for (int s = 0; s < 4; ++s) {
        int n = s * 512 + tx;
        int r = n >> 6, c2 = n & 63;
        float2 v = *(const float2*)&out[((size_t)(row0 + r)) * PP + 2 * c2];
        *(float2*)&aggL[r][2 * c2] = v;
    }
    __syncthreads();

    // wave w computes rows w*4..w*4+3; lane -> cols p0, p0+1
    int p0 = lane * 2;
    float c00 = 0.f, c01 = 0.f, c10 = 0.f, c11 = 0.f;
    float c20 = 0.f, c21 = 0.f, c30 = 0.f, c31 = 0.f;
    const float* a0 = aggL[w * 4 + 0];
    const float* a1 = aggL[w * 4 + 1];
    const float* a2r = aggL[w * 4 + 2];
    const float* a3 = aggL[w * 4 + 3];
#pragma unroll 4
    for (int qq = 0; qq < 64; ++qq) {
        uint2 wp = *(const uint2*)&w2q[qq * PP + p0];
        float w00 = __uint_as_float(wp.x << 16);
        float w01 = __uint_as_float(wp.x & 0xFFFF0000u);
        float w10 = __uint_as_float(wp.y << 16);
        float w11 = __uint_as_float(wp.y & 0xFFFF0000u);
        float2 aa;
        aa = *(const float2*)&a0[2 * qq]; c00 += aa.x * w00 + aa.y * w01; c01 += aa.x * w10 + aa.y * w11;
        aa = *(const float2*)&a1[2 * qq]; c10 += aa.x * w00 + aa.y * w01; c11 += aa.x * w10 + aa.y * w11;
        aa = *(const float2*)&a2r[2 * qq]; c20 += aa.x * w00 + aa.y * w01; c21 += aa.x * w10 + aa.y * w11;
        aa = *(const float2*)&a3[2 * qq]; c30 += aa.x * w00 + aa.y * w01; c31 += aa.x * w10 + aa.y * w11;
    }

    float2 u2 = *(const float2*)&uvb[p0];
    float2 v2 = *(const float2*)&uvb[PP + p0];
    float2 bb = *(const float2*)&uvb[2 * PP + p0];
    float2 w1 = *(const float2*)&W1[p0];
#pragma unroll
    for (int r = 0; r < 4; ++r) {
        int row = row0 + w * 4 + r;
        float xs = x[row];
        float ps = 0.f, ng = 0.f;
#pragma unroll
        for (int s = 0; s < 8; ++s) {
            ps += posP[s * MM + row];
            ng += negP[s * MM + row];
        }
        float cc0 = (r == 0) ? c00 : (r == 1) ? c10 : (r == 2) ? c20 : c30;
        float cc1 = (r == 0) ? c01 : (r == 1) ? c11 : (r == 2) ? c21 : c31;
        float o0 = cc0 + xs * w1.x + ps * u2.x + ng * v2.x + bb.x;
        float o1 = cc1 + xs * w1.y + ps * u2.y + ng * v2.y + bb.y;
        *(float2*)&out[(size_t)row * PP + p0] = make_float2(fmaxf(o0, 0.f), fmaxf(o1, 0.f));
    }
}

extern "C" void kernel_launch(void* const* d_in, const int* in_sizes, int n_in,
                              void* d_out, int out_size, void* d_ws, size_t ws_size,
                              hipStream_t stream) {
    const float* x      = (const float*)d_in[0];
    const float* mu     = (const float*)d_in[1];
    const float* weight = (const float*)d_in[2];
    const float* adj    = (const float*)d_in[3];
    const float* W1     = (const float*)d_in[4];
    const float* b1     = (const float*)d_in[5];
    const float* W2     = (const float*)d_in[6];
    const float* b2     = (const float*)d_in[7];
    const float* W3     = (const float*)d_in[8];
    const float* b3     = (const float*)d_in[9];
    const float* theta4 = (const float*)d_in[10];
    float* out = (float*)d_out;

    float* ws   = (float*)d_ws;
    float* posP = ws + POSP_OFF;
    float* negP = ws + NEGP_OFF;
    float* uvb  = ws + UVB_OFF;
    ull* maskb  = (ull*)((char*)d_ws + MASK_OFF_BYTES);

    k_uv<<<1, 256, 0, stream>>>(theta4, W3, b1, b2, b3, uvb);

    dim3 gp(NN / 128, 8, BB);
    k_prep<<<gp, 256, 0, stream>>>(weight, adj, posP, negP, maskb);

    k_gather<<<MM / 4, 256, 0, stream>>>(mu, maskb, out);

    k_gemm<<<MM / 32, 512, 0, stream>>>(x, W1, W2, posP, negP, uvb, out);
}

// Round 9
// 73.364 us; speedup vs baseline: 2.0450x; 1.1418x over previous
//
#include <hip/hip_runtime.h>

#define BB 32
#define NN 512
#define PP 128
#define MM (BB * NN)  // 16384 rows

typedef unsigned int u32;
typedef unsigned long long ull;

// ws layout (float offsets) — VERBATIM from rounds 2/5/6/7/8 (proven in-bounds)
#define POSP_OFF 0            // [8][MM] f32
#define NEGP_OFF (8 * MM)     // [8][MM] f32
#define UVB_OFF (16 * MM)     // u[128], v[128], bias[128]
#define MASK_OFF_BYTES ((size_t)(16 * MM + 512) * 4)  // [8][MM] u64, 8B-aligned

__device__ inline u32 bf16rne(float f) {
    u32 u = __float_as_uint(f);
    return (u + 0x7FFFu + ((u >> 16) & 1u)) >> 16;
}

// uv: 256 thr, two q-halves reduced in LDS. bias = b1+b2+b3. (r7 verbatim)
__global__ __launch_bounds__(256) void k_uv(const float* __restrict__ t4,
                                            const float* __restrict__ W3,
                                            const float* __restrict__ b1,
                                            const float* __restrict__ b2,
                                            const float* __restrict__ b3,
                                            float* __restrict__ uvb) {
    __shared__ float su[2][PP], sv[2][PP];
    int p = threadIdx.x & 127, h = threadIdx.x >> 7;
    float u = 0.f, v = 0.f;
#pragma unroll 8
    for (int q = h * 64; q < h * 64 + 64; ++q) {
        float t = t4[q];
        float w = W3[q * PP + p];
        u += fmaxf(t, 0.f) * w;
        v += fmaxf(-t, 0.f) * w;
    }
    su[h][p] = u;
    sv[h][p] = v;
    __syncthreads();
    if (threadIdx.x < PP) {
        uvb[p] = su[0][p] + su[1][p];
        uvb[PP + p] = sv[0][p] + sv[1][p];
        uvb[2 * PP + p] = b1[p] + b2[p] + b3[p];
    }
}

// prep REWRITE: 1024 blocks (4 j-tiles x 8 segs x 32 b), 512 thr =
// 64 j-pairs (float2) x 8 i-groups (8 i each). BRANCHLESS: adj is exactly
// 0/1 so relu(w*a) == relu(w)*a — all 16 loads/thread independent.
// Bit semantics unchanged: maskb[seg][row] bit k = adj[b, seg*64+k, j] != 0.
__global__ __launch_bounds__(512) void k_prep(const float* __restrict__ weight,
                                              const float* __restrict__ adj,
                                              float* __restrict__ posP,
                                              float* __restrict__ negP,
                                              ull* __restrict__ maskb) {
    __shared__ float sps[8][128], sng[8][128];
    __shared__ u32 sm[8][128];

    int b = blockIdx.z, seg = blockIdx.y;
    int tx = threadIdx.x;
    int jl2 = tx & 63;   // j-pair lane
    int g = tx >> 6;     // i-group 0..7 (8 i's each)
    int j0tile = blockIdx.x * 128;
    int j = j0tile + jl2 * 2;

    size_t base = (size_t)b * NN * NN + ((size_t)seg * 64 + g * 8) * NN + j;
    const float2* wp = (const float2*)(weight + base);
    const float2* ap = (const float2*)(adj + base);
    float psx = 0.f, psy = 0.f, ngx = 0.f, ngy = 0.f;
    u32 mx = 0, my = 0;
#pragma unroll
    for (int k = 0; k < 8; ++k) {
        float2 a = ap[(size_t)k * (NN / 2)];
        float2 w = wp[(size_t)k * (NN / 2)];
        float wa0 = w.x * a.x;  // a in {0,1}: wa = w or 0
        float wa1 = w.y * a.y;
        psx += fmaxf(wa0, 0.f);
        ngx += fmaxf(-wa0, 0.f);
        psy += fmaxf(wa1, 0.f);
        ngy += fmaxf(-wa1, 0.f);
        mx |= (a.x != 0.f ? 1u : 0u) << k;
        my |= (a.y != 0.f ? 1u : 0u) << k;
    }
    sps[g][2 * jl2] = psx;
    sps[g][2 * jl2 + 1] = psy;
    sng[g][2 * jl2] = ngx;
    sng[g][2 * jl2 + 1] = ngy;
    sm[g][2 * jl2] = mx;
    sm[g][2 * jl2 + 1] = my;
    __syncthreads();
    if (tx < 128) {
        float P = 0.f, Ng = 0.f;
        ull m = 0;
#pragma unroll
        for (int g2 = 0; g2 < 8; ++g2) {
            P += sps[g2][tx];
            Ng += sng[g2][tx];
            m |= (ull)sm[g2][tx] << (g2 * 8);  // group g covers i-bits [g*8, g*8+8)
        }
        int row = b * NN + j0tile + tx;
        posP[seg * MM + row] = P;
        negP[seg * MM + row] = Ng;
        maskb[(size_t)seg * MM + row] = m;
    }
}

// k_gather (r8 verbatim): 4096 blocks x 256 thr (4 waves). One row per wave.
// Writes agg fp32 into d_out (staging; k_gemm overwrites after reading).
__global__ __launch_bounds__(256) void k_gather(const float* __restrict__ mu,
                                                const ull* __restrict__ maskb,
                                                float* __restrict__ aggout) {
    int bid = blockIdx.x;
    int vbid = ((bid & 7) << 9) | (bid >> 3);  // bijective: XCD x owns 2048 consecutive rows
    int row0 = vbid * 4;
    int b = row0 >> 9;
    int tx = threadIdx.x, lane = tx & 63, w = tx >> 6;

    const float2* mub2 = (const float2*)(mu + (size_t)b * NN * PP);
    int row = row0 + w;
    float ax = 0.f, ay = 0.f;
#pragma unroll
    for (int r = 0; r < 8; ++r) {
        uint2 mw = ((const uint2*)maskb)[(size_t)r * MM + row];
        unsigned lo = __builtin_amdgcn_readfirstlane(mw.x);
        unsigned hi = __builtin_amdgcn_readfirstlane(mw.y);
        ull mask = ((ull)hi << 32) | lo;
        int ib = r * 64;
        while (mask) {
            int i0 = __builtin_ctzll(mask);
            mask &= mask - 1;
            float2 v0 = mub2[(size_t)((ib + i0) << 6) | lane];
            if (mask) {
                int i1 = __builtin_ctzll(mask);
                mask &= mask - 1;
                float2 v1 = mub2[(size_t)((ib + i1) << 6) | lane];
                if (mask) {
                    int i2 = __builtin_ctzll(mask);
                    mask &= mask - 1;
                    float2 v2 = mub2[(size_t)((ib + i2) << 6) | lane];
                    if (mask) {
                        int i3 = __builtin_ctzll(mask);
                        mask &= mask - 1;
                        float2 v3 = mub2[(size_t)((ib + i3) << 6) | lane];
                        ax += v0.x + v1.x + v2.x + v3.x;
                        ay += v0.y + v1.y + v2.y + v3.y;
                    } else {
                        ax += v0.x + v1.x + v2.x;
                        ay += v0.y + v1.y + v2.y;
                    }
                } else {
                    ax += v0.x + v1.x;
                    ay += v0.y + v1.y;
                }
            } else {
                ax += v0.x;
                ay += v0.y;
            }
        }
    }
    *(float2*)&aggout[(size_t)row * PP + 2 * lane] = make_float2(ax, ay);
}

// k_gemm (r8 verbatim): 512 blocks x 512 thr (8 waves). 32 rows/block.
__global__ __launch_bounds__(512) void k_gemm(
    const float* __restrict__ x, const float* __restrict__ W1,
    const float* __restrict__ W2, const float* __restrict__ posP,
    const float* __restrict__ negP, const float* __restrict__ uvb,
    float* __restrict__ out) {
    __shared__ float aggL[32][130];  // 16.6 KB
    __shared__ u32 w2q[64 * PP];     // 32 KB

    int bid = blockIdx.x;
    int vbid = ((bid & 7) << 6) | (bid >> 3);  // same-XCD rows as k_gather
    int row0 = vbid * 32;
    int tx = threadIdx.x, lane = tx & 63, w = tx >> 6;

#pragma unroll
    for (int s = 0; s < 16; ++s) {
        int n = s * 512 + tx;
        int qq = n >> 7, p = n & 127;
        w2q[n] = bf16rne(W2[(2 * qq) * PP + p]) | (bf16rne(W2[(2 * qq) * PP + PP + p]) << 16);
    }
#pragma unroll
    for (int s = 0; s < 4; ++s) {
        int n = s * 512 + tx;
        int r = n >> 6, c2 = n & 63;
        float2 v = *(const float2*)&out[((size_t)(row0 + r)) * PP + 2 * c2];
        *(float2*)&aggL[r][2 * c2] = v;
    }
    __syncthreads();

    int p0 = lane * 2;
    float c00 = 0.f, c01 = 0.f, c10 = 0.f, c11 = 0.f;
    float c20 = 0.f, c21 = 0.f, c30 = 0.f, c31 = 0.f;
    const float* a0 = aggL[w * 4 + 0];
    const float* a1 = aggL[w * 4 + 1];
    const float* a2r = aggL[w * 4 + 2];
    const float* a3 = aggL[w * 4 + 3];
#pragma unroll 4
    for (int qq = 0; qq < 64; ++qq) {
        uint2 wp = *(const uint2*)&w2q[qq * PP + p0];
        float w00 = __uint_as_float(wp.x << 16);
        float w01 = __uint_as_float(wp.x & 0xFFFF0000u);
        float w10 = __uint_as_float(wp.y << 16);
        float w11 = __uint_as_float(wp.y & 0xFFFF0000u);
        float2 aa;
        aa = *(const float2*)&a0[2 * qq]; c00 += aa.x * w00 + aa.y * w01; c01 += aa.x * w10 + aa.y * w11;
        aa = *(const float2*)&a1[2 * qq]; c10 += aa.x * w00 + aa.y * w01; c11 += aa.x * w10 + aa.y * w11;
        aa = *(const float2*)&a2r[2 * qq]; c20 += aa.x * w00 + aa.y * w01; c21 += aa.x * w10 + aa.y * w11;
        aa = *(const float2*)&a3[2 * qq]; c30 += aa.x * w00 + aa.y * w01; c31 += aa.x * w10 + aa.y * w11;
    }

    float2 u2 = *(const float2*)&uvb[p0];
    float2 v2 = *(const float2*)&uvb[PP + p0];
    float2 bb = *(const float2*)&uvb[2 * PP + p0];
    float2 w1 = *(const float2*)&W1[p0];
#pragma unroll
    for (int r = 0; r < 4; ++r) {
        int row = row0 + w * 4 + r;
        float xs = x[row];
        float ps = 0.f, ng = 0.f;
#pragma unroll
        for (int s = 0; s < 8; ++s) {
            ps += posP[s * MM + row];
            ng += negP[s * MM + row];
        }
        float cc0 = (r == 0) ? c00 : (r == 1) ? c10 : (r == 2) ? c20 : c30;
        float cc1 = (r == 0) ? c01 : (r == 1) ? c11 : (r == 2) ? c21 : c31;
        float o0 = cc0 + xs * w1.x + ps * u2.x + ng * v2.x + bb.x;
        float o1 = cc1 + xs * w1.y + ps * u2.y + ng * v2.y + bb.y;
        *(float2*)&out[(size_t)row * PP + p0] = make_float2(fmaxf(o0, 0.f), fmaxf(o1, 0.f));
    }
}

extern "C" void kernel_launch(void* const* d_in, const int* in_sizes, int n_in,
                              void* d_out, int out_size, void* d_ws, size_t ws_size,
                              hipStream_t stream) {
    const float* x      = (const float*)d_in[0];
    const float* mu     = (const float*)d_in[1];
    const float* weight = (const float*)d_in[2];
    const float* adj    = (const float*)d_in[3];
    const float* W1     = (const float*)d_in[4];
    const float* b1     = (const float*)d_in[5];
    const float* W2     = (const float*)d_in[6];
    const float* b2     = (const float*)d_in[7];
    const float* W3     = (const float*)d_in[8];
    const float* b3     = (const float*)d_in[9];
    const float* theta4 = (const float*)d_in[10];
    float* out = (float*)d_out;

    float* ws   = (float*)d_ws;
    float* posP = ws + POSP_OFF;
    float* negP = ws + NEGP_OFF;
    float* uvb  = ws + UVB_OFF;
    ull* maskb  = (ull*)((char*)d_ws + MASK_OFF_BYTES);

    k_uv<<<1, 256, 0, stream>>>(theta4, W3, b1, b2, b3, uvb);

    dim3 gp(NN / 128, 8, BB);
    k_prep<<<gp, 512, 0, stream>>>(weight, adj, posP, negP, maskb);

    k_gather<<<MM / 4, 256, 0, stream>>>(mu, maskb, out);

    k_gemm<<<MM / 32, 512, 0, stream>>>(x, W1, W2, posP, negP, uvb, out);
}

// Round 10
// 51.450 us; speedup vs baseline: 2.9160x; 1.4259x over previous
//
#include <hip/hip_runtime.h>

#define BB 32
#define NN 512
#define PP 128
#define MM (BB * NN)  // 16384 rows

typedef unsigned int u32;
typedef unsigned short u16;

typedef __attribute__((ext_vector_type(8))) short short8v;  // 8 bf16 (4 VGPR)
typedef __attribute__((ext_vector_type(4))) float f32x4;

// ---- ws layout ----
// float-offset region (proven lineage r2..r9)
#define POSP_OFF 0                      // [8][MM] f32
#define NEGP_OFF (8 * MM)               // [8][MM] f32
#define UVB_OFF (16 * MM)               // u[128], v[128], bias[128]
#define PFIN_OFF (16 * MM + 512)        // pos final [MM]
#define NFIN_OFF (16 * MM + 512 + MM)   // neg final [MM]
// byte-offset region (new; ws is ~268 MB per the 0xAA-fill evidence)
#define ADJB_OFF ((size_t)4194304)      // u16 [BB][NN][NN] = 16 MB, ends 20971520
#define MUTHI_OFF ((size_t)20971520)    // u16 [BB][PP][NN] = 4 MB
#define MUTLO_OFF ((size_t)25165824)    // u16 [BB][PP][NN] = 4 MB
#define W2T_OFF ((size_t)29360128)      // u16 [PP][PP] = 32 KB (W2T[p][q] = bf16(W2[q][p]))

__device__ inline u32 bf16rne(float f) {
    u32 u = __float_as_uint(f);
    return (u + 0x7FFFu + ((u >> 16) & 1u)) >> 16;
}

// prep (r9 branchless body) + NEW: writes adj as bf16 (adj in {0,1} -> exact).
// masks dropped (gather deleted).
__global__ __launch_bounds__(512) void k_prep(const float* __restrict__ weight,
                                              const float* __restrict__ adj,
                                              float* __restrict__ posP,
                                              float* __restrict__ negP,
                                              u16* __restrict__ adjb) {
    __shared__ float sps[8][128], sng[8][128];

    int b = blockIdx.z, seg = blockIdx.y;
    int tx = threadIdx.x;
    int jl2 = tx & 63;
    int g = tx >> 6;
    int j0tile = blockIdx.x * 128;
    int j = j0tile + jl2 * 2;

    size_t base = (size_t)b * NN * NN + ((size_t)seg * 64 + g * 8) * NN + j;
    const float2* wp = (const float2*)(weight + base);
    const float2* ap = (const float2*)(adj + base);
    u32* ab32 = (u32*)adjb + (base >> 1);
    float psx = 0.f, psy = 0.f, ngx = 0.f, ngy = 0.f;
#pragma unroll
    for (int k = 0; k < 8; ++k) {
        float2 a = ap[(size_t)k * (NN / 2)];
        float2 w = wp[(size_t)k * (NN / 2)];
        float wa0 = w.x * a.x;
        float wa1 = w.y * a.y;
        psx += fmaxf(wa0, 0.f);
        ngx += fmaxf(-wa0, 0.f);
        psy += fmaxf(wa1, 0.f);
        ngy += fmaxf(-wa1, 0.f);
        ab32[(size_t)k * (NN / 2)] =
            (a.x != 0.f ? 0x3F80u : 0u) | (a.y != 0.f ? 0x3F800000u : 0u);
    }
    sps[g][2 * jl2] = psx;
    sps[g][2 * jl2 + 1] = psy;
    sng[g][2 * jl2] = ngx;
    sng[g][2 * jl2 + 1] = ngy;
    __syncthreads();
    if (tx < 128) {
        float P = 0.f, Ng = 0.f;
#pragma unroll
        for (int g2 = 0; g2 < 8; ++g2) {
            P += sps[g2][tx];
            Ng += sng[g2][tx];
        }
        int row = b * NN + j0tile + tx;
        posP[seg * MM + row] = P;
        negP[seg * MM + row] = Ng;
    }
}

// aux: bid<256: mu transpose -> muT hi/lo bf16; bid 256..263: pos/neg reduce;
// bid 264: uv+bias (r7 body); bid 265: W2T bf16.
__global__ __launch_bounds__(256) void k_aux(
    const float* __restrict__ mu, const float* __restrict__ W2,
    const float* __restrict__ t4, const float* __restrict__ W3,
    const float* __restrict__ b1, const float* __restrict__ b2,
    const float* __restrict__ b3, const float* __restrict__ posP,
    const float* __restrict__ negP, float* __restrict__ posf,
    float* __restrict__ negf, float* __restrict__ uvb,
    u16* __restrict__ muthi, u16* __restrict__ mutlo, u16* __restrict__ w2t) {
    __shared__ float tile[64][132];
    __shared__ float su[2][PP], sv[2][PP];
    int bid = blockIdx.x;
    int t = threadIdx.x;
    if (bid < 256) {
        int b = bid >> 3, i0 = (bid & 7) * 64;
        const float4* mu4 = (const float4*)(mu + ((size_t)b * NN + i0) * PP);
#pragma unroll
        for (int s = 0; s < 8; ++s) {
            int n = s * 256 + t;
            int ii = n >> 5, c4 = n & 31;
            float4 v = mu4[ii * 32 + c4];
            *(float4*)&tile[ii][c4 * 4] = v;
        }
        __syncthreads();
        int p = t >> 1, half = t & 1;
        u32* hdst = (u32*)(muthi + ((size_t)b * PP + p) * NN + i0 + half * 32);
        u32* ldst = (u32*)(mutlo + ((size_t)b * PP + p) * NN + i0 + half * 32);
#pragma unroll
        for (int e2 = 0; e2 < 16; ++e2) {
            float v0 = tile[half * 32 + 2 * e2][p];
            float v1 = tile[half * 32 + 2 * e2 + 1][p];
            u32 h0 = bf16rne(v0), h1 = bf16rne(v1);
            float l0 = v0 - __uint_as_float(h0 << 16);
            float l1 = v1 - __uint_as_float(h1 << 16);
            hdst[e2] = h0 | (h1 << 16);
            ldst[e2] = bf16rne(l0) | (bf16rne(l1) << 16);
        }
    } else if (bid < 264) {
        int base = (bid - 256) * 2048;
#pragma unroll
        for (int rr = 0; rr < 8; ++rr) {
            int row = base + rr * 256 + t;
            float P = 0.f, Ng = 0.f;
#pragma unroll
            for (int s = 0; s < 8; ++s) {
                P += posP[s * MM + row];
                Ng += negP[s * MM + row];
            }
            posf[row] = P;
            negf[row] = Ng;
        }
    } else if (bid == 264) {
        int p = t & 127, h = t >> 7;
        float u = 0.f, v = 0.f;
#pragma unroll 8
        for (int q = h * 64; q < h * 64 + 64; ++q) {
            float tt = t4[q];
            float w = W3[q * PP + p];
            u += fmaxf(tt, 0.f) * w;
            v += fmaxf(-tt, 0.f) * w;
        }
        su[h][p] = u;
        sv[h][p] = v;
        __syncthreads();
        if (t < PP) {
            uvb[p] = su[0][p] + su[1][p];
            uvb[PP + p] = sv[0][p] + sv[1][p];
            uvb[2 * PP + p] = b1[p] + b2[p] + b3[p];
        }
    } else {
#pragma unroll 4
        for (int c = 0; c < 64; ++c) {
            int n = c * 256 + t;
            int q = n >> 7, pp = n & 127;
            w2t[pp * PP + q] = (u16)bf16rne(W2[q * PP + pp]);
        }
    }
}

// fused: agg = adj @ mu via MFMA (mu hi/lo), agg hi/lo -> LDS,
// out = relu(agg@W2 (MFMA, W2T bf16) + x*W1 + pos*u + neg*v + bias).
// 256 blocks = 32 b x 8 jtiles(64). 256 thr = 4 waves; wave w owns p-slice [32w,32w+32).
__global__ __launch_bounds__(256) void k_fused(
    const u16* __restrict__ adjb, const u16* __restrict__ muthi,
    const u16* __restrict__ mutlo, const u16* __restrict__ w2t,
    const float* __restrict__ x, const float* __restrict__ W1,
    const float* __restrict__ posf, const float* __restrict__ negf,
    const float* __restrict__ uvb, float* __restrict__ out) {
    __shared__ __align__(16) u16 pool[32768];  // 64 KB
    // phase1 carve: adjL [64][72] @0; muhiL [128][72] @4608; muloL [128][72] @13824
    u16* adjL = pool;
    u16* mhiL = pool + 4608;
    u16* mloL = pool + 13824;
    // phase2 carve (aliases, barrier-separated): w2L [128][128 swz] @0;
    // agghi [64][128 swz] @16384; agglo @24576
    u16* w2L = pool;
    u16* ahiL = pool + 16384;
    u16* aloL = pool + 24576;

    int bid = blockIdx.x;
    int vbid = ((bid & 7) << 5) | (bid >> 3);  // XCD chunking: 4 b's per XCD
    int b = vbid >> 3;
    int j0 = (vbid & 7) * 64;
    int tx = threadIdx.x, lane = tx & 63, w = tx >> 6;

    const u16* adjrow = adjb + ((size_t)b * NN + j0) * NN;
    const u16* mhG = muthi + (size_t)b * PP * NN;
    const u16* mlG = mutlo + (size_t)b * PP * NN;

    f32x4 acc[4][2];  // [jt][pt]
#pragma unroll
    for (int a = 0; a < 4; ++a)
#pragma unroll
        for (int c = 0; c < 2; ++c) acc[a][c] = (f32x4){0.f, 0.f, 0.f, 0.f};

    for (int step = 0; step < 8; ++step) {
        int k0 = step * 64;
        {  // stage adj tile 64x64
            int jj = tx >> 2, kk0 = (tx & 3) * 16;
            const uint4* src = (const uint4*)(adjrow + (size_t)jj * NN + k0 + kk0);
            uint4 v0 = src[0], v1 = src[1];
            *(uint4*)&adjL[jj * 72 + kk0] = v0;
            *(uint4*)&adjL[jj * 72 + kk0 + 8] = v1;
        }
        {  // stage muT hi/lo tiles 128x64
            int p = tx >> 1, kk0 = (tx & 1) * 32;
            const uint4* sh = (const uint4*)(mhG + (size_t)p * NN + k0 + kk0);
            const uint4* sl = (const uint4*)(mlG + (size_t)p * NN + k0 + kk0);
#pragma unroll
            for (int c = 0; c < 4; ++c) {
                *(uint4*)&mhiL[p * 72 + kk0 + c * 8] = sh[c];
                *(uint4*)&mloL[p * 72 + kk0 + c * 8] = sl[c];
            }
        }
        __syncthreads();
#pragma unroll
        for (int ks = 0; ks < 2; ++ks) {
            int kb = ks * 32 + (lane >> 4) * 8;
            short8v afr[4];
#pragma unroll
            for (int jt = 0; jt < 4; ++jt)
                afr[jt] = *(const short8v*)&adjL[(jt * 16 + (lane & 15)) * 72 + kb];
#pragma unroll
            for (int pt = 0; pt < 2; ++pt) {
                int prow = w * 32 + pt * 16 + (lane & 15);
                short8v bh = *(const short8v*)&mhiL[prow * 72 + kb];
                short8v bl = *(const short8v*)&mloL[prow * 72 + kb];
#pragma unroll
                for (int jt = 0; jt < 4; ++jt) {
                    acc[jt][pt] = __builtin_amdgcn_mfma_f32_16x16x32_bf16(afr[jt], bh, acc[jt][pt], 0, 0, 0);
                    acc[jt][pt] = __builtin_amdgcn_mfma_f32_16x16x32_bf16(afr[jt], bl, acc[jt][pt], 0, 0, 0);
                }
            }
        }
        __syncthreads();
    }

    // acc -> agg hi/lo (XOR-swizzled cols) ; stage W2T (same swizzle)
    {
#pragma unroll
        for (int jt = 0; jt < 4; ++jt)
#pragma unroll
            for (int pt = 0; pt < 2; ++pt)
#pragma unroll
                for (int r = 0; r < 4; ++r) {
                    int j = jt * 16 + (lane >> 4) * 4 + r;
                    int q = w * 32 + pt * 16 + (lane & 15);
                    float v = acc[jt][pt][r];
                    u32 h = bf16rne(v);
                    float lf = v - __uint_as_float(h << 16);
                    int qs = q ^ ((j & 7) << 3);
                    ahiL[j * 128 + qs] = (u16)h;
                    aloL[j * 128 + qs] = (u16)bf16rne(lf);
                }
        int p = tx >> 1, qc = (tx & 1) * 64;
        const uint4* src = (const uint4*)(w2t + p * PP + qc);
#pragma unroll
        for (int c = 0; c < 8; ++c) {
            int q8 = (qc + c * 8) ^ ((p & 7) << 3);
            *(uint4*)&w2L[p * 128 + q8] = src[c];
        }
    }
    __syncthreads();

    // phase 2: D2[j][p'] = sum_q agg[j][q] * W2[q][p']
    f32x4 acc2[4][2];  // [jt][nt]
#pragma unroll
    for (int a = 0; a < 4; ++a)
#pragma unroll
        for (int c = 0; c < 2; ++c) acc2[a][c] = (f32x4){0.f, 0.f, 0.f, 0.f};
#pragma unroll
    for (int ks = 0; ks < 4; ++ks) {
        int kb = ks * 32 + (lane >> 4) * 8;
        short8v bfr[2];
#pragma unroll
        for (int nt = 0; nt < 2; ++nt) {
            int prow = w * 32 + nt * 16 + (lane & 15);
            bfr[nt] = *(const short8v*)&w2L[prow * 128 + (kb ^ ((prow & 7) << 3))];
        }
#pragma unroll
        for (int jt = 0; jt < 4; ++jt) {
            int jrow = jt * 16 + (lane & 15);
            short8v ah = *(const short8v*)&ahiL[jrow * 128 + (kb ^ ((jrow & 7) << 3))];
            short8v al = *(const short8v*)&aloL[jrow * 128 + (kb ^ ((jrow & 7) << 3))];
#pragma unroll
            for (int nt = 0; nt < 2; ++nt) {
                acc2[jt][nt] = __builtin_amdgcn_mfma_f32_16x16x32_bf16(ah, bfr[nt], acc2[jt][nt], 0, 0, 0);
                acc2[jt][nt] = __builtin_amdgcn_mfma_f32_16x16x32_bf16(al, bfr[nt], acc2[jt][nt], 0, 0, 0);
            }
        }
    }

    // epilogue
    float u_[2], v_[2], bb_[2], w1_[2];
#pragma unroll
    for (int nt = 0; nt < 2; ++nt) {
        int pp = w * 32 + nt * 16 + (lane & 15);
        u_[nt] = uvb[pp];
        v_[nt] = uvb[PP + pp];
        bb_[nt] = uvb[2 * PP + pp];
        w1_[nt] = W1[pp];
    }
    int row0 = b * NN + j0;
#pragma unroll
    for (int jt = 0; jt < 4; ++jt)
#pragma unroll
        for (int r = 0; r < 4; ++r) {
            int row = row0 + jt * 16 + (lane >> 4) * 4 + r;
            float xs = x[row];
            float ps = posf[row];
            float ng = negf[row];
#pragma unroll
            for (int nt = 0; nt < 2; ++nt) {
                int pp = w * 32 + nt * 16 + (lane & 15);
                float o = acc2[jt][nt][r] + xs * w1_[nt] + ps * u_[nt] + ng * v_[nt] + bb_[nt];
                out[(size_t)row * PP + pp] = fmaxf(o, 0.f);
            }
        }
}

extern "C" void kernel_launch(void* const* d_in, const int* in_sizes, int n_in,
                              void* d_out, int out_size, void* d_ws, size_t ws_size,
                              hipStream_t stream) {
    const float* x      = (const float*)d_in[0];
    const float* mu     = (const float*)d_in[1];
    const float* weight = (const float*)d_in[2];
    const float* adj    = (const float*)d_in[3];
    const float* W1     = (const float*)d_in[4];
    const float* b1     = (const float*)d_in[5];
    const float* W2     = (const float*)d_in[6];
    const float* b2     = (const float*)d_in[7];
    const float* W3     = (const float*)d_in[8];
    const float* b3     = (const float*)d_in[9];
    const float* theta4 = (const float*)d_in[10];
    float* out = (float*)d_out;

    float* ws   = (float*)d_ws;
    float* posP = ws + POSP_OFF;
    float* negP = ws + NEGP_OFF;
    float* uvb  = ws + UVB_OFF;
    float* posf = ws + PFIN_OFF;
    float* negf = ws + NFIN_OFF;
    u16* adjb   = (u16*)((char*)d_ws + ADJB_OFF);
    u16* muthi  = (u16*)((char*)d_ws + MUTHI_OFF);
    u16* mutlo  = (u16*)((char*)d_ws + MUTLO_OFF);
    u16* w2t    = (u16*)((char*)d_ws + W2T_OFF);

    dim3 gp(NN / 128, 8, BB);
    k_prep<<<gp, 512, 0, stream>>>(weight, adj, posP, negP, adjb);

    k_aux<<<266, 256, 0, stream>>>(mu, W2, theta4, W3, b1, b2, b3, posP, negP,
                                   posf, negf, uvb, muthi, mutlo, w2t);

    k_fused<<<256, 256, 0, stream>>>(adjb, muthi, mutlo, w2t, x, W1, posf, negf,
                                     uvb, out);
}